// Round 1
// baseline (1077.410 us; speedup 1.0000x reference)
//
#include <hip/hip_runtime.h>
#include <hip/hip_bf16.h>

#define T_SEQ 1024
#define BATCH 512
#define INPUT 64
#define HID   128

typedef __attribute__((ext_vector_type(8))) short bf16x8;
typedef __attribute__((ext_vector_type(4))) float f32x4;

__device__ __forceinline__ short f2bf(float f) {
    union { float f; unsigned u; } v; v.f = f;
    unsigned r = (v.u + 0x7FFFu + ((v.u >> 16) & 1u)) >> 16;
    return (short)(r & 0xFFFFu);
}

__device__ __forceinline__ float fast_tanh(float x) {
    float cx = fminf(fmaxf(x, -9.0f), 9.0f);
    float e = __expf(2.0f * cx);               // v_exp_f32 path
    return (e - 1.0f) * __builtin_amdgcn_rcpf(e + 1.0f);
}

__device__ __forceinline__ float hsig(float v) {
    return fminf(fmaxf(v * 0.16666666666666666f + 0.5f, 0.0f), 1.0f);
}

// ---------------- Stage 1: recurrence ----------------
// 32 blocks x 256 threads. Block handles 16 batches; wave w handles hidden cols [32w,32w+32).
__global__ __launch_bounds__(256) void rnn_kernel(
    const float* __restrict__ x,
    const float* __restrict__ W_ih, const float* __restrict__ b_ih,
    const float* __restrict__ W_hh, const float* __restrict__ b_hh,
    const float* __restrict__ W_gate, const float* __restrict__ b_gate,
    float* __restrict__ agg_out)
{
    __shared__ short sh_h[2][16][136];   // pitch 136 bf16 = 272B (17*16B): aligned b128, 2-way conflicts only

    const int tid  = threadIdx.x;
    const int wave = tid >> 6, lane = tid & 63;
    const int quad = lane >> 4, l15 = lane & 15;
    const int b0 = blockIdx.x * 16;
    const int n0 = wave * 32;

    // ---- one-time: weights -> bf16 B-fragments in registers ----
    // B[k][n] layout: lane holds B[quad*8+j][l15] => W[n][k..k+7] contiguous reads.
    bf16x8 w1[2][6], wg[2][4];
    for (int tn = 0; tn < 2; ++tn) {
        int n = n0 + tn * 16 + l15;
        for (int kb = 0; kb < 6; ++kb) {
            const float* p = (kb < 2) ? (W_ih + n * INPUT + kb * 32 + quad * 8)
                                      : (W_hh + n * HID + (kb - 2) * 32 + quad * 8);
            bf16x8 f;
            for (int j = 0; j < 8; ++j) f[j] = f2bf(p[j]);
            w1[tn][kb] = f;
        }
        for (int kb = 0; kb < 4; ++kb) {
            const float* p = W_gate + n * HID + kb * 32 + quad * 8;
            bf16x8 f;
            for (int j = 0; j < 8; ++j) f[j] = f2bf(p[j]);
            wg[tn][kb] = f;
        }
    }
    float bias1[2], biasg[2];
    for (int tn = 0; tn < 2; ++tn) {
        int n = n0 + tn * 16 + l15;
        bias1[tn] = b_ih[n] + b_hh[n];
        biasg[tn] = b_gate[n];
    }

    f32x4 agg0, agg1;
    for (int r = 0; r < 4; ++r) { agg0[r] = 0.0f; agg1[r] = 0.0f; }

    bf16x8 hf[4];                        // h A-fragments; h0 = 0
    for (int kb = 0; kb < 4; ++kb)
        for (int j = 0; j < 8; ++j) hf[kb][j] = 0;

    // prefetch x for t=0: A[m=l15][k=kb*32+quad*8+j]
    const float* xbase = x + ((long)(b0 + l15) * T_SEQ) * INPUT + quad * 8;
    f32x4 px0 = *(const f32x4*)(xbase);
    f32x4 px1 = *(const f32x4*)(xbase + 4);
    f32x4 px2 = *(const f32x4*)(xbase + 32);
    f32x4 px3 = *(const f32x4*)(xbase + 36);

    for (int t = 0; t < T_SEQ; ++t) {
        // convert prefetched x to bf16 A-frags
        bf16x8 xa0, xa1;
        for (int j = 0; j < 4; ++j) {
            xa0[j] = f2bf(px0[j]); xa0[4 + j] = f2bf(px1[j]);
            xa1[j] = f2bf(px2[j]); xa1[4 + j] = f2bf(px3[j]);
        }
        // issue prefetch for t+1 (covers HBM latency behind this step's compute)
        {
            int tn_ = (t + 1 < T_SEQ) ? t + 1 : T_SEQ - 1;
            const float* xp = x + (((long)(b0 + l15) * T_SEQ) + tn_) * INPUT + quad * 8;
            px0 = *(const f32x4*)(xp);
            px1 = *(const f32x4*)(xp + 4);
            px2 = *(const f32x4*)(xp + 32);
            px3 = *(const f32x4*)(xp + 36);
        }

        // h_new = tanh([x_t | h_t] @ [W_ih^T; W_hh^T] + b_ih + b_hh)
        f32x4 acc0, acc1;
        for (int r = 0; r < 4; ++r) { acc0[r] = bias1[0]; acc1[r] = bias1[1]; }
        acc0 = __builtin_amdgcn_mfma_f32_16x16x32_bf16(xa0, w1[0][0], acc0, 0, 0, 0);
        acc1 = __builtin_amdgcn_mfma_f32_16x16x32_bf16(xa0, w1[1][0], acc1, 0, 0, 0);
        acc0 = __builtin_amdgcn_mfma_f32_16x16x32_bf16(xa1, w1[0][1], acc0, 0, 0, 0);
        acc1 = __builtin_amdgcn_mfma_f32_16x16x32_bf16(xa1, w1[1][1], acc1, 0, 0, 0);
        for (int kb = 0; kb < 4; ++kb) {
            acc0 = __builtin_amdgcn_mfma_f32_16x16x32_bf16(hf[kb], w1[0][2 + kb], acc0, 0, 0, 0);
            acc1 = __builtin_amdgcn_mfma_f32_16x16x32_bf16(hf[kb], w1[1][2 + kb], acc1, 0, 0, 0);
        }

        float hn[8];
        for (int r = 0; r < 4; ++r) { hn[r] = fast_tanh(acc0[r]); hn[4 + r] = fast_tanh(acc1[r]); }

        // write h_new (C-layout) into LDS [batch][hidden], double-buffered
        const int buf = t & 1;
        for (int r = 0; r < 4; ++r) {
            int m = quad * 4 + r;
            sh_h[buf][m][n0 + l15]      = f2bf(hn[r]);
            sh_h[buf][m][n0 + 16 + l15] = f2bf(hn[4 + r]);
        }
        __syncthreads();
        // read A-frags of h_new (used by gate GEMM now AND GEMM1 next step)
        for (int kb = 0; kb < 4; ++kb)
            hf[kb] = *(const bf16x8*)&sh_h[buf][l15][kb * 32 + quad * 8];

        // gate = hardsigmoid(h_new @ W_gate^T + b_gate)
        f32x4 g0, g1;
        for (int r = 0; r < 4; ++r) { g0[r] = biasg[0]; g1[r] = biasg[1]; }
        for (int kb = 0; kb < 4; ++kb) {
            g0 = __builtin_amdgcn_mfma_f32_16x16x32_bf16(hf[kb], wg[0][kb], g0, 0, 0, 0);
            g1 = __builtin_amdgcn_mfma_f32_16x16x32_bf16(hf[kb], wg[1][kb], g1, 0, 0, 0);
        }
        for (int r = 0; r < 4; ++r) {
            agg0[r] += hn[r]     * hsig(g0[r]);
            agg1[r] += hn[4 + r] * hsig(g1[r]);
        }
    }

    const float s = 1.0f / (float)T_SEQ;
    for (int r = 0; r < 4; ++r) {
        int m = quad * 4 + r;
        agg_out[(b0 + m) * HID + n0 + l15]      = agg0[r] * s;
        agg_out[(b0 + m) * HID + n0 + 16 + l15] = agg1[r] * s;
    }
}

// ---------------- Stage 2a: mapped = agg @ W_map^T + b_map ----------------
// grid 4096: 32 M-tiles (16 batches) x 128 N-blocks (128 cols). Writes into d_out.
__global__ __launch_bounds__(256) void map_kernel(
    const float* __restrict__ agg, const float* __restrict__ W_map,
    const float* __restrict__ b_map, float* __restrict__ mapped)
{
    const int tid  = threadIdx.x;
    const int wave = tid >> 6, lane = tid & 63;
    const int quad = lane >> 4, l15 = lane & 15;
    const int mb = blockIdx.x & 31;
    const int nb = blockIdx.x >> 5;
    const int b0 = mb * 16;
    const int n0 = nb * 128 + wave * 32;

    bf16x8 af[4];
    for (int kb = 0; kb < 4; ++kb) {
        const float* p = agg + (b0 + l15) * HID + kb * 32 + quad * 8;
        bf16x8 f;
        for (int j = 0; j < 8; ++j) f[j] = f2bf(p[j]);
        af[kb] = f;
    }
    for (int tn = 0; tn < 2; ++tn) {
        int n = n0 + tn * 16 + l15;
        float bias = b_map[n];
        f32x4 c;
        for (int r = 0; r < 4; ++r) c[r] = bias;
        for (int kb = 0; kb < 4; ++kb) {
            const float* p = W_map + (long)n * HID + kb * 32 + quad * 8;
            bf16x8 f;
            for (int j = 0; j < 8; ++j) f[j] = f2bf(p[j]);
            c = __builtin_amdgcn_mfma_f32_16x16x32_bf16(af[kb], f, c, 0, 0, 0);
        }
        for (int r = 0; r < 4; ++r) {
            int m = quad * 4 + r;
            mapped[(long)(b0 + m) * 16384 + n] = c[r];
        }
    }
}

// ---------------- Stage 2b: pool 4x4 -> hardsigmoid -> gate (in place) ----------------
// one block per (b,c) plane of 32x32; 256 threads x float4.
__global__ __launch_bounds__(256) void pool_gate_kernel(float* __restrict__ mapped)
{
    __shared__ float sh_part[256];
    __shared__ float sh_gate[64];
    const int tid = threadIdx.x;
    float* plane = mapped + (long)blockIdx.x * 1024;

    f32x4 m4 = *(const f32x4*)(plane + tid * 4);   // h = tid>>3, w-block = tid&7
    sh_part[tid] = m4[0] + m4[1] + m4[2] + m4[3];
    __syncthreads();
    if (tid < 64) {
        int ph = tid >> 3, pw = tid & 7;
        float s = 0.0f;
        for (int i = 0; i < 4; ++i) s += sh_part[(4 * ph + i) * 8 + pw];
        sh_gate[tid] = hsig(s * (1.0f / 16.0f));
    }
    __syncthreads();
    int h = tid >> 3, wb = tid & 7;
    float g = sh_gate[(h >> 2) * 8 + wb];
    f32x4 o = m4 * g;
    *(f32x4*)(plane + tid * 4) = o;
}

extern "C" void kernel_launch(void* const* d_in, const int* in_sizes, int n_in,
                              void* d_out, int out_size, void* d_ws, size_t ws_size,
                              hipStream_t stream) {
    const float* x      = (const float*)d_in[0];
    const float* W_ih   = (const float*)d_in[1];
    const float* b_ih   = (const float*)d_in[2];
    const float* W_hh   = (const float*)d_in[3];
    const float* b_hh   = (const float*)d_in[4];
    const float* W_gate = (const float*)d_in[5];
    const float* b_gate = (const float*)d_in[6];
    const float* W_map  = (const float*)d_in[7];
    const float* b_map  = (const float*)d_in[8];
    float* out = (float*)d_out;
    float* agg = (float*)d_ws;            // 512*128*4 = 256 KB scratch

    rnn_kernel<<<32, 256, 0, stream>>>(x, W_ih, b_ih, W_hh, b_hh, W_gate, b_gate, agg);
    map_kernel<<<4096, 256, 0, stream>>>(agg, W_map, b_map, out);
    pool_gate_kernel<<<512 * 16, 256, 0, stream>>>(out);
}